// Round 1
// baseline (203.166 us; speedup 1.0000x reference)
//
#include <hip/hip_runtime.h>
#include <hip/hip_bf16.h>

// Problem constants (from reference): B=256, T=256, V=1000, SD=AD=64.
#define BB 256
#define TT 256
#define ADIM 64

// Reference output: out[b,t,a] = start_state[b,a] + (t/255) * patterns[id[b],t,a]
// Everything else in the reference (LSTM stack etc.) is dead code (del'd).

static __device__ __forceinline__ float bf16_bits_to_f32(unsigned short u) {
    return __uint_as_float(((unsigned int)u) << 16);
}

static __device__ __forceinline__ unsigned short f32_to_bf16_rne(float f) {
    unsigned int x = __float_as_uint(f);
    unsigned int r = x + 0x7fffu + ((x >> 16) & 1u);  // round-to-nearest-even
    return (unsigned short)(r >> 16);
}

// One kernel: per-block dtype probe (uniform branch) + gather-FMA.
// Each thread handles 8 consecutive 'a' elements -> 16B vector I/O in both paths.
__global__ __launch_bounds__(256) void traj_kernel(
    const void* __restrict__ start,     // (B, 64)  fp32 or bf16
    const int*  __restrict__ ids,       // (B,)
    const void* __restrict__ patterns,  // (V, T, 64) fp32 or bf16
    void*       __restrict__ out)       // (B, T, 64) same dtype as inputs
{
    // ---- dtype probe: bf16-interpret first 256 elems of start_state.
    // If buffer is fp32, half of these are low-mantissa halves -> random
    // exponents -> some |v| > 1e4 with overwhelming probability.
    __shared__ int s_isbf;
    if (threadIdx.x == 0) s_isbf = 1;
    __syncthreads();
    {
        unsigned short u = ((const unsigned short*)start)[threadIdx.x];
        float v = bf16_bits_to_f32(u);
        if (!(fabsf(v) <= 1.0e4f)) s_isbf = 0;   // catches big values and NaN
    }
    __syncthreads();
    const bool isbf = (s_isbf != 0);

    // ---- index math: idx covers B*T*8 threads, 8 'a'-elements each
    int idx = blockIdx.x * 256 + threadIdx.x;     // 0 .. 524287
    int a0  = (idx & 7) << 3;                     // 0,8,...,56
    int t   = (idx >> 3) & (TT - 1);
    int b   = idx >> 11;

    float w  = (float)t * (1.0f / 255.0f);        // linspace(0,1,256)[t]
    int   id = ids[b];

    long long poff = (((long long)id * TT) + t) * ADIM + a0;
    long long soff = ((long long)b) * ADIM + a0;
    long long ooff = (((long long)b * TT) + t) * ADIM + a0;

    if (isbf) {
        const uint4* sp = reinterpret_cast<const uint4*>((const unsigned short*)start + soff);
        const uint4* pp = reinterpret_cast<const uint4*>((const unsigned short*)patterns + poff);
        uint4* op = reinterpret_cast<uint4*>((unsigned short*)out + ooff);
        uint4 sv = *sp;
        uint4 pv = *pp;
        const unsigned short* s16 = reinterpret_cast<const unsigned short*>(&sv);
        const unsigned short* p16 = reinterpret_cast<const unsigned short*>(&pv);
        uint4 ov;
        unsigned short* o16 = reinterpret_cast<unsigned short*>(&ov);
#pragma unroll
        for (int i = 0; i < 8; ++i) {
            float s = bf16_bits_to_f32(s16[i]);
            float p = bf16_bits_to_f32(p16[i]);
            o16[i] = f32_to_bf16_rne(fmaf(w, p, s));
        }
        *op = ov;
    } else {
        const float4* sp = reinterpret_cast<const float4*>((const float*)start + soff);
        const float4* pp = reinterpret_cast<const float4*>((const float*)patterns + poff);
        float4* op = reinterpret_cast<float4*>((float*)out + ooff);
        float4 s0 = sp[0], s1 = sp[1];
        float4 p0 = pp[0], p1 = pp[1];
        float4 r0, r1;
        r0.x = fmaf(w, p0.x, s0.x); r0.y = fmaf(w, p0.y, s0.y);
        r0.z = fmaf(w, p0.z, s0.z); r0.w = fmaf(w, p0.w, s0.w);
        r1.x = fmaf(w, p1.x, s1.x); r1.y = fmaf(w, p1.y, s1.y);
        r1.z = fmaf(w, p1.z, s1.z); r1.w = fmaf(w, p1.w, s1.w);
        op[0] = r0;
        op[1] = r1;
    }
}

extern "C" void kernel_launch(void* const* d_in, const int* in_sizes, int n_in,
                              void* d_out, int out_size, void* d_ws, size_t ws_size,
                              hipStream_t stream) {
    // setup_inputs() dict order: 0=start_state, 1=instruction_id, ..., 27=patterns
    const void* start    = d_in[0];
    const int*  ids      = (const int*)d_in[1];
    int pat_idx = n_in - 1;
    // defensive: patterns is the unique input with V*T*AD = 16,384,000 elems
    for (int i = 0; i < n_in; ++i) {
        if (in_sizes[i] == 1000 * 256 * 64) { pat_idx = i; break; }
    }
    const void* patterns = d_in[pat_idx];

    // B*T*8 threads / 256 = 2048 blocks
    traj_kernel<<<2048, 256, 0, stream>>>(start, ids, patterns, d_out);
}